// Round 1
// baseline (1542.061 us; speedup 1.0000x reference)
//
#include <hip/hip_runtime.h>
#include <hip/hip_bf16.h>

// Problem constants (hardcoded in the reference module)
constexpr int Bc = 32;    // batch
constexpr int Sc = 2048;  // sequence length
constexpr int Tc = 64;    // tables
constexpr int Cc = 512;   // columns
constexpr int Lc = 16;    // tokens per span
constexpr int Dc = 768;   // hidden
constexpr int Hc = 8;     // heads
constexpr int DHc = 96;   // head dim

// ---------------------------------------------------------------------------
// 1) Ragged gather + sum pooling: one block per (b, row) where row covers T
//    table rows then C column rows. 256 threads, 3 f32 elems each (D=768).
// ---------------------------------------------------------------------------
__global__ __launch_bounds__(256) void pool_kernel(
    const float* __restrict__ seq, const int* __restrict__ tab_ids,
    const int* __restrict__ col_ids, float* __restrict__ tabp,
    float* __restrict__ colp) {
  int blk = blockIdx.x;
  int b = blk / (Tc + Cc);
  int r = blk % (Tc + Cc);
  const int* ids;
  float* outp;
  if (r < Tc) {
    ids = tab_ids + ((size_t)b * Tc + r) * Lc;
    outp = tabp + ((size_t)b * Tc + r) * Dc;
  } else {
    int c = r - Tc;
    ids = col_ids + ((size_t)b * Cc + c) * Lc;
    outp = colp + ((size_t)b * Cc + c) * Dc;
  }
  int tid = threadIdx.x;
  float a0 = 0.f, a1 = 0.f, a2 = 0.f;
#pragma unroll
  for (int l = 0; l < Lc; ++l) {
    size_t base = ((size_t)b * Sc + ids[l]) * Dc;
    a0 += seq[base + tid];
    a1 += seq[base + tid + 256];
    a2 += seq[base + tid + 512];
  }
  outp[tid] = a0;
  outp[tid + 256] = a1;
  outp[tid + 512] = a2;
}

// ---------------------------------------------------------------------------
// 2) Generic tiled f32 GEMM:  C = act(A[M,K] @ B + bias)
//    TRANSB=false: B is [K,N] row-major (x @ W)
//    TRANSB=true : B is [N,K] row-major (x @ W.T)
//    64x64 tile, BK=16, 256 threads, 4x4 acc per thread, float4 LDS reads.
// ---------------------------------------------------------------------------
template <bool TRANSB, bool LEAKY>
__global__ __launch_bounds__(256) void gemm_f32(
    const float* __restrict__ A, const float* __restrict__ Bm,
    const float* __restrict__ bias, float* __restrict__ Cout, int M, int N,
    int K) {
  constexpr int BM = 64, BN = 64, BK = 16, PAD = 4;
  __shared__ float As[BK][BM + PAD];  // row stride 68 f32 = 272B (16B aligned)
  __shared__ float Bs[BK][BN + PAD];
  int tid = threadIdx.x;
  int tx = tid & 15, ty = tid >> 4;
  int row0 = blockIdx.y * BM, col0 = blockIdx.x * BN;
  float acc[4][4] = {};
  for (int k0 = 0; k0 < K; k0 += BK) {
#pragma unroll
    for (int i = 0; i < 4; ++i) {
      int e = tid + i * 256;
      int m = e >> 4, kk = e & 15;
      As[kk][m] = A[(size_t)(row0 + m) * K + k0 + kk];
    }
    if (TRANSB) {
#pragma unroll
      for (int i = 0; i < 4; ++i) {
        int e = tid + i * 256;
        int nn = e >> 4, kk = e & 15;
        Bs[kk][nn] = Bm[(size_t)(col0 + nn) * K + k0 + kk];
      }
    } else {
#pragma unroll
      for (int i = 0; i < 4; ++i) {
        int e = tid + i * 256;
        int kk = e >> 6, nn = e & 63;
        Bs[kk][nn] = Bm[(size_t)(k0 + kk) * N + col0 + nn];
      }
    }
    __syncthreads();
#pragma unroll
    for (int kk = 0; kk < BK; ++kk) {
      float4 a4 = *reinterpret_cast<const float4*>(&As[kk][ty * 4]);
      float4 b4 = *reinterpret_cast<const float4*>(&Bs[kk][tx * 4]);
      float av[4] = {a4.x, a4.y, a4.z, a4.w};
      float bv[4] = {b4.x, b4.y, b4.z, b4.w};
#pragma unroll
      for (int i = 0; i < 4; ++i)
#pragma unroll
        for (int j = 0; j < 4; ++j) acc[i][j] += av[i] * bv[j];
    }
    __syncthreads();
  }
#pragma unroll
  for (int i = 0; i < 4; ++i) {
    int r = row0 + ty * 4 + i;
    float4 o;
    float* op = &o.x;
#pragma unroll
    for (int j = 0; j < 4; ++j) {
      int c = col0 + tx * 4 + j;
      float vv = acc[i][j] + (bias ? bias[c] : 0.0f);
      if (LEAKY) vv = vv >= 0.f ? vv : 0.01f * vv;
      op[j] = vv;
    }
    *reinterpret_cast<float4*>(&Cout[(size_t)r * N + col0 + tx * 4]) = o;
  }
}

// ---------------------------------------------------------------------------
// 3) Bucket columns by table (CSR): one block per batch.
// ---------------------------------------------------------------------------
__global__ __launch_bounds__(256) void bucket_kernel(
    const int* __restrict__ t_of_c, int* __restrict__ col_sorted,
    int* __restrict__ offs) {
  int b = blockIdx.x, tid = threadIdx.x;
  __shared__ int cnt[Tc];
  __shared__ int cur[Tc + 1];
  if (tid < Tc) cnt[tid] = 0;
  __syncthreads();
  for (int c = tid; c < Cc; c += 256) atomicAdd(&cnt[t_of_c[b * Cc + c]], 1);
  __syncthreads();
  if (tid == 0) {
    int off = 0;
    for (int t = 0; t < Tc; ++t) {
      cur[t] = off;
      off += cnt[t];
    }
    cur[Tc] = off;
  }
  __syncthreads();
  if (tid <= Tc) offs[b * (Tc + 1) + tid] = cur[tid];
  __syncthreads();
  for (int c = tid; c < Cc; c += 256) {
    int t = t_of_c[b * Cc + c];
    int pos = atomicAdd(&cur[t], 1);
    col_sorted[b * Cc + pos] = c;
  }
}

// ---------------------------------------------------------------------------
// 4) Masked cross-attention: one block per (b,t), 256 threads = 8 heads x 32.
//    Exploits that each table attends only over its own columns (n per CSR);
//    n==0 falls back to uniform weights over all C (matches reference's
//    softmax over all -1e9 scores).
// ---------------------------------------------------------------------------
__global__ __launch_bounds__(256) void attn_kernel(
    const float* __restrict__ q, const float* __restrict__ k,
    const float* __restrict__ v, const int* __restrict__ col_sorted,
    const int* __restrict__ offs, float* __restrict__ ctx) {
  int b = blockIdx.x / Tc;
  int t = blockIdx.x % Tc;
  __shared__ float qs[Dc];
  __shared__ float pbuf[Hc][Cc];
  __shared__ float den[Hc];
  __shared__ int cols_s[Cc];
  int tid = threadIdx.x;
  for (int i = tid; i < Dc; i += 256) qs[i] = q[((size_t)b * Tc + t) * Dc + i];
  int o0 = offs[b * (Tc + 1) + t];
  int o1 = offs[b * (Tc + 1) + t + 1];
  int n = o1 - o0;
  for (int i = tid; i < n; i += 256)
    cols_s[i] = col_sorted[(size_t)b * Cc + o0 + i];
  __syncthreads();
  int h = tid >> 5, l32 = tid & 31;
  const float scale = 0.1020620726159658f;  // 1/sqrt(96)
  if (n > 0) {
    float lmax = -3.0e38f;
    for (int j = l32; j < n; j += 32) {
      const float* kr = k + ((size_t)b * Cc + cols_s[j]) * Dc + h * DHc;
      float s = 0.f;
#pragma unroll 8
      for (int d = 0; d < DHc; ++d) s += qs[h * DHc + d] * kr[d];
      s *= scale;
      pbuf[h][j] = s;
      lmax = fmaxf(lmax, s);
    }
#pragma unroll
    for (int m = 16; m >= 1; m >>= 1) lmax = fmaxf(lmax, __shfl_xor(lmax, m));
    float lsum = 0.f;
    for (int j = l32; j < n; j += 32) {
      float e = __expf(pbuf[h][j] - lmax);
      pbuf[h][j] = e;
      lsum += e;
    }
#pragma unroll
    for (int m = 16; m >= 1; m >>= 1) lsum += __shfl_xor(lsum, m);
    if (l32 == 0) den[h] = lsum;
  }
  __syncthreads();
  // ctx accumulation: 32 lanes over head-dim, 3 reps cover 96
#pragma unroll
  for (int rep = 0; rep < 3; ++rep) {
    int d = l32 + rep * 32;
    float acc = 0.f;
    if (n > 0) {
      for (int j = 0; j < n; ++j)
        acc += pbuf[h][j] * v[((size_t)b * Cc + cols_s[j]) * Dc + h * DHc + d];
      acc /= den[h];
    } else {
      for (int c = 0; c < Cc; ++c)
        acc += v[((size_t)b * Cc + c) * Dc + h * DHc + d];
      acc *= (1.0f / Cc);
    }
    ctx[((size_t)b * Tc + t) * Dc + h * DHc + d] = acc;
  }
}

// ---------------------------------------------------------------------------
// 5) residual add + L2 normalize: one block per table row.
// ---------------------------------------------------------------------------
__global__ __launch_bounds__(256) void addnorm_kernel(
    const float* __restrict__ tab, const float* __restrict__ proj,
    float* __restrict__ tabn) {
  int row = blockIdx.x;
  int tid = threadIdx.x;
  size_t base = (size_t)row * Dc;
  float x0 = tab[base + tid] + proj[base + tid];
  float x1 = tab[base + tid + 256] + proj[base + tid + 256];
  float x2 = tab[base + tid + 512] + proj[base + tid + 512];
  float ss = x0 * x0 + x1 * x1 + x2 * x2;
#pragma unroll
  for (int m = 32; m >= 1; m >>= 1) ss += __shfl_xor(ss, m);
  __shared__ float red[4];
  int wave = tid >> 6, lane = tid & 63;
  if (lane == 0) red[wave] = ss;
  __syncthreads();
  float total = red[0] + red[1] + red[2] + red[3];
  float sc = 1.0f / fmaxf(sqrtf(total), 1e-12f);
  tabn[base + tid] = x0 * sc;
  tabn[base + tid + 256] = x1 * sc;
  tabn[base + tid + 512] = x2 * sc;
}

// ---------------------------------------------------------------------------
// 6) final 256->2 head projection, straight into d_out [B, T+C, 2].
//    One wave per output row.
// ---------------------------------------------------------------------------
__global__ __launch_bounds__(256) void head2_kernel(
    const float* __restrict__ h1t, const float* __restrict__ h1c,
    const float* __restrict__ W_t2, const float* __restrict__ b_t2,
    const float* __restrict__ W_c2, const float* __restrict__ b_c2,
    float* __restrict__ out) {
  int w = threadIdx.x >> 6;
  int lane = threadIdx.x & 63;
  int row = blockIdx.x * 4 + w;  // < B*(T+C)
  int b = row / (Tc + Cc);
  int r = row % (Tc + Cc);
  const float* h1;
  const float* W2;
  const float* b2;
  if (r < Tc) {
    h1 = h1t + ((size_t)b * Tc + r) * 256;
    W2 = W_t2;
    b2 = b_t2;
  } else {
    h1 = h1c + ((size_t)b * Cc + (r - Tc)) * 256;
    W2 = W_c2;
    b2 = b_c2;
  }
  float a0 = 0.f, a1 = 0.f;
  for (int i = lane; i < 256; i += 64) {
    float x = h1[i];
    a0 += x * W2[2 * i];
    a1 += x * W2[2 * i + 1];
  }
#pragma unroll
  for (int m = 32; m >= 1; m >>= 1) {
    a0 += __shfl_xor(a0, m);
    a1 += __shfl_xor(a1, m);
  }
  if (lane == 0) {
    out[(size_t)row * 2] = a0 + b2[0];
    out[(size_t)row * 2 + 1] = a1 + b2[1];
  }
}

// ---------------------------------------------------------------------------
extern "C" void kernel_launch(void* const* d_in, const int* in_sizes, int n_in,
                              void* d_out, int out_size, void* d_ws,
                              size_t ws_size, hipStream_t stream) {
  const float* seq = (const float*)d_in[0];
  const int* tab_ids = (const int*)d_in[1];
  const int* col_ids = (const int*)d_in[2];
  const int* t_of_c = (const int*)d_in[3];
  const float* W_tab_pool = (const float*)d_in[4];
  const float* b_tab_pool = (const float*)d_in[5];
  const float* W_col_pool = (const float*)d_in[6];
  const float* b_col_pool = (const float*)d_in[7];
  const float* in_proj_w = (const float*)d_in[8];
  const float* in_proj_b = (const float*)d_in[9];
  const float* out_proj_w = (const float*)d_in[10];
  const float* out_proj_b = (const float*)d_in[11];
  const float* W_t1 = (const float*)d_in[12];
  const float* b_t1 = (const float*)d_in[13];
  const float* W_t2 = (const float*)d_in[14];
  const float* b_t2 = (const float*)d_in[15];
  const float* W_c1 = (const float*)d_in[16];
  const float* b_c1 = (const float*)d_in[17];
  const float* W_c2 = (const float*)d_in[18];
  const float* b_c2 = (const float*)d_in[19];
  float* out = (float*)d_out;

  // Workspace layout (f32), with reuse:
  //   tabp (later reused as q, then as out_proj output)
  //   colp (later reused as k)
  size_t szBT_D = (size_t)Bc * Tc * Dc;  // 1,572,864
  size_t szBC_D = (size_t)Bc * Cc * Dc;  // 12,582,912
  float* f = (float*)d_ws;
  float* tabp = f; f += szBT_D;              // pooled tables / q / proj
  float* colp = f; f += szBC_D;              // pooled cols / k
  float* colb = f; f += szBC_D;              // col (post pool-linear)
  float* tabb = f; f += szBT_D;              // tab (post pool-linear)
  float* vbuf = f; f += szBC_D;              // v
  float* ctxb = f; f += szBT_D;              // attention context
  float* tabn = f; f += szBT_D;              // normalized tab
  float* h1t = f; f += (size_t)Bc * Tc * 256;
  float* h1c = f; f += (size_t)Bc * Cc * 256;
  int* col_sorted = (int*)f;
  int* offs = col_sorted + Bc * Cc;

  float* qbuf = tabp;   // reuse after pool-linear consumed tabp
  float* kbuf = colp;   // reuse after pool-linear consumed colp
  float* projb = tabp;  // reuse after attention consumed q

  // 1) column bucketing (independent) + pooling
  bucket_kernel<<<Bc, 256, 0, stream>>>(t_of_c, col_sorted, offs);
  pool_kernel<<<Bc * (Tc + Cc), 256, 0, stream>>>(seq, tab_ids, col_ids, tabp,
                                                  colp);
  // 2) pool-linear + leaky
  gemm_f32<false, true><<<dim3(Dc / 64, (Bc * Tc) / 64), 256, 0, stream>>>(
      tabp, W_tab_pool, b_tab_pool, tabb, Bc * Tc, Dc, Dc);
  gemm_f32<false, true><<<dim3(Dc / 64, (Bc * Cc) / 64), 256, 0, stream>>>(
      colp, W_col_pool, b_col_pool, colb, Bc * Cc, Dc, Dc);
  // 3) q/k/v projections (x @ W.T + b)
  gemm_f32<true, false><<<dim3(Dc / 64, (Bc * Tc) / 64), 256, 0, stream>>>(
      tabb, in_proj_w, in_proj_b, qbuf, Bc * Tc, Dc, Dc);
  gemm_f32<true, false><<<dim3(Dc / 64, (Bc * Cc) / 64), 256, 0, stream>>>(
      colb, in_proj_w + (size_t)Dc * Dc, in_proj_b + Dc, kbuf, Bc * Cc, Dc,
      Dc);
  gemm_f32<true, false><<<dim3(Dc / 64, (Bc * Cc) / 64), 256, 0, stream>>>(
      colb, in_proj_w + (size_t)2 * Dc * Dc, in_proj_b + 2 * Dc, vbuf, Bc * Cc,
      Dc, Dc);
  // 4) masked per-table cross-attention
  attn_kernel<<<Bc * Tc, 256, 0, stream>>>(qbuf, kbuf, vbuf, col_sorted, offs,
                                           ctxb);
  // 5) output projection + residual + L2 normalize
  gemm_f32<true, false><<<dim3(Dc / 64, (Bc * Tc) / 64), 256, 0, stream>>>(
      ctxb, out_proj_w, out_proj_b, projb, Bc * Tc, Dc, Dc);
  addnorm_kernel<<<Bc * Tc, 256, 0, stream>>>(tabb, projb, tabn);
  // 6) classification heads
  gemm_f32<false, true><<<dim3(256 / 64, (Bc * Tc) / 64), 256, 0, stream>>>(
      tabn, W_t1, b_t1, h1t, Bc * Tc, 256, Dc);
  gemm_f32<false, true><<<dim3(256 / 64, (Bc * Cc) / 64), 256, 0, stream>>>(
      colb, W_c1, b_c1, h1c, Bc * Cc, 256, Dc);
  head2_kernel<<<(Bc * (Tc + Cc)) / 4, 256, 0, stream>>>(h1t, h1c, W_t2, b_t2,
                                                         W_c2, b_c2, out);
}

// Round 2
// 627.403 us; speedup vs baseline: 2.4578x; 2.4578x over previous
//
#include <hip/hip_runtime.h>
#include <hip/hip_bf16.h>

constexpr int Bc = 32;    // batch
constexpr int Sc = 2048;  // sequence length
constexpr int Tc = 64;    // tables
constexpr int Cc = 512;   // columns
constexpr int Lc = 16;    // tokens per span
constexpr int Dc = 768;   // hidden
constexpr int Hc = 8;     // heads
constexpr int DHc = 96;   // head dim

typedef __attribute__((ext_vector_type(4))) float f32x4;
typedef __attribute__((ext_vector_type(8))) short bf16x8;  // 8 bf16 in 4 VGPRs

__device__ inline unsigned short f2bf(float f) {
  __hip_bfloat16 h = __float2bfloat16(f);
  return *reinterpret_cast<unsigned short*>(&h);
}
__device__ inline float bf2f(__hip_bfloat16 h) { return __bfloat162float(h); }

#define GLDS16(gp, lp)                                                        \
  __builtin_amdgcn_global_load_lds(                                           \
      (const __attribute__((address_space(1))) void*)(gp),                    \
      (__attribute__((address_space(3))) void*)(lp), 16, 0, 0)

// ---------------------------------------------------------------------------
// 1) Ragged gather + sum pooling -> bf16. One wave per output row; lanes hold
//    3 float4 (192 float4 = 768 f32 per row). Writes packed bf16 (ushort4).
// ---------------------------------------------------------------------------
__global__ __launch_bounds__(256) void pool_kernel(
    const float* __restrict__ seq, const int* __restrict__ tab_ids,
    const int* __restrict__ col_ids, __hip_bfloat16* __restrict__ tabp,
    __hip_bfloat16* __restrict__ colp) {
  int w = threadIdx.x >> 6, l = threadIdx.x & 63;
  int row = blockIdx.x * 4 + w;
  int b = row / (Tc + Cc), r = row % (Tc + Cc);
  const int* ids;
  __hip_bfloat16* outp;
  if (r < Tc) {
    ids = tab_ids + ((size_t)b * Tc + r) * Lc;
    outp = tabp + ((size_t)b * Tc + r) * Dc;
  } else {
    int c = r - Tc;
    ids = col_ids + ((size_t)b * Cc + c) * Lc;
    outp = colp + ((size_t)b * Cc + c) * Dc;
  }
  float4 a0 = {0, 0, 0, 0}, a1 = {0, 0, 0, 0}, a2 = {0, 0, 0, 0};
#pragma unroll
  for (int t = 0; t < Lc; ++t) {
    const float4* p =
        reinterpret_cast<const float4*>(seq + ((size_t)b * Sc + ids[t]) * Dc);
    float4 v0 = p[l], v1 = p[l + 64], v2 = p[l + 128];
    a0.x += v0.x; a0.y += v0.y; a0.z += v0.z; a0.w += v0.w;
    a1.x += v1.x; a1.y += v1.y; a1.z += v1.z; a1.w += v1.w;
    a2.x += v2.x; a2.y += v2.y; a2.z += v2.z; a2.w += v2.w;
  }
  ushort4* ob = reinterpret_cast<ushort4*>(outp);
  ob[l] = make_ushort4(f2bf(a0.x), f2bf(a0.y), f2bf(a0.z), f2bf(a0.w));
  ob[l + 64] = make_ushort4(f2bf(a1.x), f2bf(a1.y), f2bf(a1.z), f2bf(a1.w));
  ob[l + 128] = make_ushort4(f2bf(a2.x), f2bf(a2.y), f2bf(a2.z), f2bf(a2.w));
}

// ---------------------------------------------------------------------------
// 2) Weight conversion: f32 [K][N] -> bf16 [N][K] (tiled transpose)
// ---------------------------------------------------------------------------
__global__ __launch_bounds__(256) void convt_kernel(
    const float* __restrict__ in, __hip_bfloat16* __restrict__ out, int K,
    int N) {
  __shared__ float t[32][33];
  int bx = blockIdx.x * 32, by = blockIdx.y * 32;
  int x = threadIdx.x & 31, y = threadIdx.x >> 5;  // 32 x 8
#pragma unroll
  for (int i = 0; i < 32; i += 8) t[y + i][x] = in[(size_t)(by + y + i) * N + bx + x];
  __syncthreads();
#pragma unroll
  for (int i = 0; i < 32; i += 8)
    out[(size_t)(bx + y + i) * K + by + x] = __float2bfloat16(t[x][y + i]);
}

// plain f32 -> bf16 (layout preserved), 4 elems/thread
__global__ __launch_bounds__(256) void conv_kernel(
    const float4* __restrict__ in, ushort4* __restrict__ out, int n4) {
  int i = blockIdx.x * 256 + threadIdx.x;
  if (i < n4) {
    float4 v = in[i];
    out[i] = make_ushort4(f2bf(v.x), f2bf(v.y), f2bf(v.z), f2bf(v.w));
  }
}

// ---------------------------------------------------------------------------
// 3) bf16 MFMA GEMM (m97 structure): out = act(A[M,K] @ Bt[N,K]^T + bias)
//    128x128 tile, BK=32, 4 waves, 4x4 16x16x32 fragments per wave,
//    global_load_lds width-16 staging, single-buffered 2-barrier loop.
//    OUTMODE: 0 = bf16 out, 1 = f32 out, 2 = both.
// ---------------------------------------------------------------------------
template <int OUTMODE, bool LEAKY>
__global__ __launch_bounds__(256) void gemm_bf16(
    const __hip_bfloat16* __restrict__ A, const __hip_bfloat16* __restrict__ Bt,
    const float* __restrict__ bias, __hip_bfloat16* __restrict__ Obf,
    float* __restrict__ Of32, int M, int N, int K) {
  constexpr int BM = 128, BN = 128, BK = 32;
  __shared__ __hip_bfloat16 As[BM * BK];
  __shared__ __hip_bfloat16 Bs[BN * BK];
  int tid = threadIdx.x;
  int row0 = blockIdx.y * BM, col0 = blockIdx.x * BN;
  int w = tid >> 6, l = tid & 63;
  int wr = (w >> 1) * 64, wc = (w & 1) * 64;
  f32x4 acc[4][4];
#pragma unroll
  for (int m = 0; m < 4; ++m)
#pragma unroll
    for (int n = 0; n < 4; ++n) acc[m][n] = f32x4{0.f, 0.f, 0.f, 0.f};

  // staging map: thread tid covers bf16 elems [tid*8, tid*8+8) of the 128x32
  // tile (linear row-major [row][32]); row = tid/4, kk = (tid%4)*8
  int srow = tid >> 2;
  int skk = (tid & 3) * 8;
  const __hip_bfloat16* gA = A + (size_t)(row0 + srow) * K + skk;
  const __hip_bfloat16* gB = Bt + (size_t)(col0 + srow) * K + skk;
  char* lA = (char*)As + tid * 16;
  char* lB = (char*)Bs + tid * 16;
  int lr = l & 15, lk = (l >> 4) * 8;

  for (int k0 = 0; k0 < K; k0 += BK) {
    GLDS16(gA + k0, lA);
    GLDS16(gA + k0 + (size_t)64 * K, lA + 4096);
    GLDS16(gB + k0, lB);
    GLDS16(gB + k0 + (size_t)64 * K, lB + 4096);
    __syncthreads();  // drains vmcnt before barrier
    bf16x8 af[4], bfr[4];
#pragma unroll
    for (int m = 0; m < 4; ++m)
      af[m] = *reinterpret_cast<const bf16x8*>(&As[(wr + m * 16 + lr) * BK + lk]);
#pragma unroll
    for (int n = 0; n < 4; ++n)
      bfr[n] = *reinterpret_cast<const bf16x8*>(&Bs[(wc + n * 16 + lr) * BK + lk]);
#pragma unroll
    for (int m = 0; m < 4; ++m)
#pragma unroll
      for (int n = 0; n < 4; ++n)
        acc[m][n] = __builtin_amdgcn_mfma_f32_16x16x32_bf16(af[m], bfr[n],
                                                            acc[m][n], 0, 0, 0);
    __syncthreads();
  }

  // C/D layout (m89/m91 verified): col = lane&15, row = (lane>>4)*4 + reg
  int colI = l & 15, rowb = (l >> 4) * 4;
#pragma unroll
  for (int m = 0; m < 4; ++m) {
#pragma unroll
    for (int n = 0; n < 4; ++n) {
      int c = col0 + wc + n * 16 + colI;
      float bv = bias ? bias[c] : 0.f;
#pragma unroll
      for (int j = 0; j < 4; ++j) {
        int r = row0 + wr + m * 16 + rowb + j;
        float v = acc[m][n][j] + bv;
        if (LEAKY) v = v >= 0.f ? v : 0.01f * v;
        if (OUTMODE == 0 || OUTMODE == 2)
          Obf[(size_t)r * N + c] = __float2bfloat16(v);
        if (OUTMODE == 1 || OUTMODE == 2) Of32[(size_t)r * N + c] = v;
      }
    }
  }
}

// ---------------------------------------------------------------------------
// 4) Bucket columns by table (CSR): one block per batch.
// ---------------------------------------------------------------------------
__global__ __launch_bounds__(256) void bucket_kernel(
    const int* __restrict__ t_of_c, int* __restrict__ col_sorted,
    int* __restrict__ offs) {
  int b = blockIdx.x, tid = threadIdx.x;
  __shared__ int cnt[Tc];
  __shared__ int cur[Tc + 1];
  if (tid < Tc) cnt[tid] = 0;
  __syncthreads();
  for (int c = tid; c < Cc; c += 256) atomicAdd(&cnt[t_of_c[b * Cc + c]], 1);
  __syncthreads();
  if (tid == 0) {
    int off = 0;
    for (int t = 0; t < Tc; ++t) {
      cur[t] = off;
      off += cnt[t];
    }
    cur[Tc] = off;
  }
  __syncthreads();
  if (tid <= Tc) offs[b * (Tc + 1) + tid] = cur[tid];
  __syncthreads();
  for (int c = tid; c < Cc; c += 256) {
    int t = t_of_c[b * Cc + c];
    int pos = atomicAdd(&cur[t], 1);
    col_sorted[b * Cc + pos] = c;
  }
}

// ---------------------------------------------------------------------------
// 5) Masked cross-attention over bf16 q / kv (kv: [B*C][1536], k|v halves).
//    One block per (b,t), 8 heads x 32 lanes. n==0 -> uniform over all C.
// ---------------------------------------------------------------------------
__global__ __launch_bounds__(256) void attn_kernel(
    const __hip_bfloat16* __restrict__ q, const __hip_bfloat16* __restrict__ kv,
    const int* __restrict__ col_sorted, const int* __restrict__ offs,
    __hip_bfloat16* __restrict__ ctx) {
  int b = blockIdx.x / Tc;
  int t = blockIdx.x % Tc;
  __shared__ float qs[Dc];
  __shared__ float pbuf[Hc][Cc];
  __shared__ float den[Hc];
  __shared__ int cols_s[Cc];
  int tid = threadIdx.x;
  for (int i = tid; i < Dc; i += 256)
    qs[i] = bf2f(q[((size_t)b * Tc + t) * Dc + i]);
  int o0 = offs[b * (Tc + 1) + t];
  int o1 = offs[b * (Tc + 1) + t + 1];
  int n = o1 - o0;
  for (int i = tid; i < n; i += 256)
    cols_s[i] = col_sorted[(size_t)b * Cc + o0 + i];
  __syncthreads();
  int h = tid >> 5, l32 = tid & 31;
  const float scale = 0.10206207261596577f;  // 1/sqrt(96)
  if (n > 0) {
    float lmax = -3.0e38f;
    for (int j = l32; j < n; j += 32) {
      const __hip_bfloat16* kr = kv + ((size_t)b * Cc + cols_s[j]) * 1536 + h * DHc;
      float s = 0.f;
#pragma unroll 8
      for (int d = 0; d < DHc; ++d) s += qs[h * DHc + d] * bf2f(kr[d]);
      s *= scale;
      pbuf[h][j] = s;
      lmax = fmaxf(lmax, s);
    }
#pragma unroll
    for (int m = 16; m >= 1; m >>= 1) lmax = fmaxf(lmax, __shfl_xor(lmax, m));
    float lsum = 0.f;
    for (int j = l32; j < n; j += 32) {
      float e = __expf(pbuf[h][j] - lmax);
      pbuf[h][j] = e;
      lsum += e;
    }
#pragma unroll
    for (int m = 16; m >= 1; m >>= 1) lsum += __shfl_xor(lsum, m);
    if (l32 == 0) den[h] = lsum;
  }
  __syncthreads();
#pragma unroll
  for (int rep = 0; rep < 3; ++rep) {
    int d = l32 + rep * 32;
    float acc = 0.f;
    if (n > 0) {
      for (int j = 0; j < n; ++j)
        acc += pbuf[h][j] *
               bf2f(kv[((size_t)b * Cc + cols_s[j]) * 1536 + 768 + h * DHc + d]);
      acc /= den[h];
    } else {
      for (int c = 0; c < Cc; ++c)
        acc += bf2f(kv[((size_t)b * Cc + c) * 1536 + 768 + h * DHc + d]);
      acc *= (1.0f / Cc);
    }
    ctx[((size_t)b * Tc + t) * Dc + h * DHc + d] = __float2bfloat16(acc);
  }
}

// ---------------------------------------------------------------------------
// 6) residual add + L2 normalize (f32 in, bf16 out)
// ---------------------------------------------------------------------------
__global__ __launch_bounds__(256) void addnorm_kernel(
    const float* __restrict__ tab, const float* __restrict__ proj,
    __hip_bfloat16* __restrict__ tabn) {
  int row = blockIdx.x;
  int tid = threadIdx.x;
  size_t base = (size_t)row * Dc;
  float x0 = tab[base + tid] + proj[base + tid];
  float x1 = tab[base + tid + 256] + proj[base + tid + 256];
  float x2 = tab[base + tid + 512] + proj[base + tid + 512];
  float ss = x0 * x0 + x1 * x1 + x2 * x2;
#pragma unroll
  for (int m = 32; m >= 1; m >>= 1) ss += __shfl_xor(ss, m);
  __shared__ float red[4];
  int wave = tid >> 6, lane = tid & 63;
  if (lane == 0) red[wave] = ss;
  __syncthreads();
  float total = red[0] + red[1] + red[2] + red[3];
  float sc = 1.0f / fmaxf(sqrtf(total), 1e-12f);
  tabn[base + tid] = __float2bfloat16(x0 * sc);
  tabn[base + tid + 256] = __float2bfloat16(x1 * sc);
  tabn[base + tid + 512] = __float2bfloat16(x2 * sc);
}

// ---------------------------------------------------------------------------
// 7) final 256->2 head projection into d_out [B, T+C, 2]. One wave per row.
// ---------------------------------------------------------------------------
__global__ __launch_bounds__(256) void head2_kernel(
    const float* __restrict__ h1t, const float* __restrict__ h1c,
    const float* __restrict__ W_t2, const float* __restrict__ b_t2,
    const float* __restrict__ W_c2, const float* __restrict__ b_c2,
    float* __restrict__ out) {
  int w = threadIdx.x >> 6;
  int lane = threadIdx.x & 63;
  int row = blockIdx.x * 4 + w;
  int b = row / (Tc + Cc);
  int r = row % (Tc + Cc);
  const float* h1;
  const float* W2;
  const float* b2;
  if (r < Tc) {
    h1 = h1t + ((size_t)b * Tc + r) * 256;
    W2 = W_t2;
    b2 = b_t2;
  } else {
    h1 = h1c + ((size_t)b * Cc + (r - Tc)) * 256;
    W2 = W_c2;
    b2 = b_c2;
  }
  float a0 = 0.f, a1 = 0.f;
  for (int i = lane; i < 256; i += 64) {
    float x = h1[i];
    a0 += x * W2[2 * i];
    a1 += x * W2[2 * i + 1];
  }
#pragma unroll
  for (int m = 32; m >= 1; m >>= 1) {
    a0 += __shfl_xor(a0, m);
    a1 += __shfl_xor(a1, m);
  }
  if (lane == 0) {
    out[(size_t)row * 2] = a0 + b2[0];
    out[(size_t)row * 2 + 1] = a1 + b2[1];
  }
}

// ---------------------------------------------------------------------------
extern "C" void kernel_launch(void* const* d_in, const int* in_sizes, int n_in,
                              void* d_out, int out_size, void* d_ws,
                              size_t ws_size, hipStream_t stream) {
  const float* seq = (const float*)d_in[0];
  const int* tab_ids = (const int*)d_in[1];
  const int* col_ids = (const int*)d_in[2];
  const int* t_of_c = (const int*)d_in[3];
  const float* W_tab_pool = (const float*)d_in[4];
  const float* b_tab_pool = (const float*)d_in[5];
  const float* W_col_pool = (const float*)d_in[6];
  const float* b_col_pool = (const float*)d_in[7];
  const float* in_proj_w = (const float*)d_in[8];
  const float* in_proj_b = (const float*)d_in[9];
  const float* out_proj_w = (const float*)d_in[10];
  const float* out_proj_b = (const float*)d_in[11];
  const float* W_t1 = (const float*)d_in[12];
  const float* b_t1 = (const float*)d_in[13];
  const float* W_t2 = (const float*)d_in[14];
  const float* b_t2 = (const float*)d_in[15];
  const float* W_c1 = (const float*)d_in[16];
  const float* b_c1 = (const float*)d_in[17];
  const float* W_c2 = (const float*)d_in[18];
  const float* b_c2 = (const float*)d_in[19];
  float* out = (float*)d_out;

  typedef __hip_bfloat16 bf;
  char* p = (char*)d_ws;
  auto alloc = [&](size_t bytes) -> char* {
    char* r = p;
    p += (bytes + 255) & ~(size_t)255;
    return r;
  };
  const size_t nBT = (size_t)Bc * Tc;   // 2048
  const size_t nBC = (size_t)Bc * Cc;   // 16384
  bf* tabp = (bf*)alloc(nBT * Dc * 2);
  bf* colp = (bf*)alloc(nBC * Dc * 2);
  bf* tabb_bf = (bf*)alloc(nBT * Dc * 2);
  float* tabb_f = (float*)alloc(nBT * Dc * 4);
  bf* colb = (bf*)alloc(nBC * Dc * 2);
  bf* qb = (bf*)alloc(nBT * Dc * 2);
  bf* kvb = (bf*)alloc(nBC * 1536 * 2);
  bf* ctxb = (bf*)alloc(nBT * Dc * 2);
  float* projb = (float*)alloc(nBT * Dc * 4);
  bf* tabn = (bf*)alloc(nBT * Dc * 2);
  float* h1t = (float*)alloc(nBT * 256 * 4);
  float* h1c = (float*)alloc(nBC * 256 * 4);
  bf* wtab_t = (bf*)alloc((size_t)Dc * Dc * 2);
  bf* wcol_t = (bf*)alloc((size_t)Dc * Dc * 2);
  bf* winproj = (bf*)alloc((size_t)3 * Dc * Dc * 2);
  bf* woutproj = (bf*)alloc((size_t)Dc * Dc * 2);
  bf* wt1_t = (bf*)alloc((size_t)256 * Dc * 2);
  bf* wc1_t = (bf*)alloc((size_t)256 * Dc * 2);
  int* col_sorted = (int*)alloc(nBC * 4);
  int* offs = (int*)alloc((size_t)Bc * (Tc + 1) * 4);

  // weight conversions (every call; no persistent state allowed)
  convt_kernel<<<dim3(Dc / 32, Dc / 32), 256, 0, stream>>>(W_tab_pool, wtab_t, Dc, Dc);
  convt_kernel<<<dim3(Dc / 32, Dc / 32), 256, 0, stream>>>(W_col_pool, wcol_t, Dc, Dc);
  conv_kernel<<<(3 * Dc * Dc / 4) / 256, 256, 0, stream>>>(
      (const float4*)in_proj_w, (ushort4*)winproj, 3 * Dc * Dc / 4);
  conv_kernel<<<(Dc * Dc / 4) / 256, 256, 0, stream>>>(
      (const float4*)out_proj_w, (ushort4*)woutproj, Dc * Dc / 4);
  convt_kernel<<<dim3(256 / 32, Dc / 32), 256, 0, stream>>>(W_t1, wt1_t, Dc, 256);
  convt_kernel<<<dim3(256 / 32, Dc / 32), 256, 0, stream>>>(W_c1, wc1_t, Dc, 256);

  bucket_kernel<<<Bc, 256, 0, stream>>>(t_of_c, col_sorted, offs);
  pool_kernel<<<Bc * (Tc + Cc) / 4, 256, 0, stream>>>(seq, tab_ids, col_ids,
                                                      tabp, colp);
  // pool linears (+leaky)
  gemm_bf16<2, true><<<dim3(Dc / 128, nBT / 128), 256, 0, stream>>>(
      tabp, wtab_t, b_tab_pool, tabb_bf, tabb_f, nBT, Dc, Dc);
  gemm_bf16<0, true><<<dim3(Dc / 128, nBC / 128), 256, 0, stream>>>(
      colp, wcol_t, b_col_pool, colb, nullptr, nBC, Dc, Dc);
  // q and fused kv projections
  gemm_bf16<0, false><<<dim3(Dc / 128, nBT / 128), 256, 0, stream>>>(
      tabb_bf, winproj, in_proj_b, qb, nullptr, nBT, Dc, Dc);
  gemm_bf16<0, false><<<dim3(1536 / 128, nBC / 128), 256, 0, stream>>>(
      colb, winproj + (size_t)Dc * Dc, in_proj_b + Dc, kvb, nullptr, nBC, 1536,
      Dc);
  // attention
  attn_kernel<<<Bc * Tc, 256, 0, stream>>>(qb, kvb, col_sorted, offs, ctxb);
  // out projection (f32) + residual + L2 norm
  gemm_bf16<1, false><<<dim3(Dc / 128, nBT / 128), 256, 0, stream>>>(
      ctxb, woutproj, out_proj_b, nullptr, projb, nBT, Dc, Dc);
  addnorm_kernel<<<nBT, 256, 0, stream>>>(tabb_f, projb, tabn);
  // heads
  gemm_bf16<1, true><<<dim3(256 / 128, nBT / 128), 256, 0, stream>>>(
      tabn, wt1_t, b_t1, nullptr, h1t, nBT, 256, Dc);
  gemm_bf16<1, true><<<dim3(256 / 128, nBC / 128), 256, 0, stream>>>(
      colb, wc1_t, b_c1, nullptr, h1c, nBC, 256, Dc);
  head2_kernel<<<(Bc * (Tc + Cc)) / 4, 256, 0, stream>>>(h1t, h1c, W_t2, b_t2,
                                                         W_c2, b_c2, out);
}

// Round 3
// 603.646 us; speedup vs baseline: 2.5546x; 1.0394x over previous
//
#include <hip/hip_runtime.h>
#include <hip/hip_bf16.h>

constexpr int Bc = 32;    // batch
constexpr int Sc = 2048;  // sequence length
constexpr int Tc = 64;    // tables
constexpr int Cc = 512;   // columns
constexpr int Lc = 16;    // tokens per span
constexpr int Dc = 768;   // hidden
constexpr int Hc = 8;     // heads
constexpr int DHc = 96;   // head dim

typedef __attribute__((ext_vector_type(4))) float f32x4;
typedef __attribute__((ext_vector_type(8))) short bf16x8;  // 8 bf16 in 4 VGPRs
typedef __hip_bfloat16 bf;

__device__ inline unsigned short f2bf(float f) {
  __hip_bfloat16 h = __float2bfloat16(f);
  return *reinterpret_cast<unsigned short*>(&h);
}
__device__ inline float us2f(unsigned short u) {
  return __uint_as_float(((unsigned)u) << 16);
}

#define GLDS16(gp, lp)                                                        \
  __builtin_amdgcn_global_load_lds(                                           \
      (const __attribute__((address_space(1))) void*)(gp),                    \
      (__attribute__((address_space(3))) void*)(lp), 16, 0, 0)

// ---------------------------------------------------------------------------
// 0) Fused prep: all weight conversions (+transposes) and d_out bias-init in
//    ONE launch. Region dispatch by blockIdx.x.
//    blocks [0,576)        : W_tab_pool 768x768 [K][N] -> bf16 [N][K]
//    blocks [576,1152)     : W_col_pool          "
//    blocks [1152,1344)    : W_t1 768x256  -> bf16 [256][768]
//    blocks [1344,1536)    : W_c1 768x256  -> bf16 [256][768]
//    blocks [1536,3264)    : in_proj  plain f32->bf16 (already [N][K])
//    blocks [3264,3840)    : out_proj plain f32->bf16
//    blocks [3840,3984)    : d_out init with head biases (atomic targets)
// ---------------------------------------------------------------------------
__device__ inline void transpose32(const float* __restrict__ in,
                                   bf* __restrict__ outp, int K, int N,
                                   int ti, float (*t)[33]) {
  int nx = N >> 5;
  int bx = (ti % nx) * 32, by = (ti / nx) * 32;
  int x = threadIdx.x & 31, y = threadIdx.x >> 5;  // 32 x 8
#pragma unroll
  for (int i = 0; i < 32; i += 8)
    t[y + i][x] = in[(size_t)(by + y + i) * N + bx + x];
  __syncthreads();
#pragma unroll
  for (int i = 0; i < 32; i += 8)
    outp[(size_t)(bx + y + i) * K + by + x] = __float2bfloat16(t[x][y + i]);
}

__global__ __launch_bounds__(256) void prep_kernel(
    const float* __restrict__ W_tab_pool, const float* __restrict__ W_col_pool,
    const float* __restrict__ W_t1, const float* __restrict__ W_c1,
    const float* __restrict__ in_proj_w, const float* __restrict__ out_proj_w,
    const float* __restrict__ b_t2, const float* __restrict__ b_c2,
    bf* __restrict__ wtab_t, bf* __restrict__ wcol_t, bf* __restrict__ wt1_t,
    bf* __restrict__ wc1_t, bf* __restrict__ winproj, bf* __restrict__ woutproj,
    float* __restrict__ outd) {
  __shared__ float t[32][33];
  int blk = blockIdx.x, tid = threadIdx.x;
  if (blk < 576) {
    transpose32(W_tab_pool, wtab_t, Dc, Dc, blk, t);
  } else if (blk < 1152) {
    transpose32(W_col_pool, wcol_t, Dc, Dc, blk - 576, t);
  } else if (blk < 1344) {
    transpose32(W_t1, wt1_t, Dc, 256, blk - 1152, t);
  } else if (blk < 1536) {
    transpose32(W_c1, wc1_t, Dc, 256, blk - 1344, t);
  } else if (blk < 3264) {
    int i = (blk - 1536) * 256 + tid;  // < 442368 exactly
    float4 v = reinterpret_cast<const float4*>(in_proj_w)[i];
    reinterpret_cast<ushort4*>(winproj)[i] =
        make_ushort4(f2bf(v.x), f2bf(v.y), f2bf(v.z), f2bf(v.w));
  } else if (blk < 3840) {
    int i = (blk - 3264) * 256 + tid;  // < 147456 exactly
    float4 v = reinterpret_cast<const float4*>(out_proj_w)[i];
    reinterpret_cast<ushort4*>(woutproj)[i] =
        make_ushort4(f2bf(v.x), f2bf(v.y), f2bf(v.z), f2bf(v.w));
  } else {
    int e = (blk - 3840) * 256 + tid;  // < 36864 exactly
    int i = e & 1;
    int r = (e >> 1) % (Tc + Cc);
    outd[e] = (r < Tc) ? b_t2[i] : b_c2[i];
  }
}

// ---------------------------------------------------------------------------
// 1) Ragged gather + sum pooling -> bf16. One wave per output row. XCD-chunked
//    blockIdx swizzle so each XCD streams a contiguous set of batches (L2
//    locality on seq gathers).
// ---------------------------------------------------------------------------
__global__ __launch_bounds__(256) void pool_kernel(
    const float* __restrict__ seq, const int* __restrict__ tab_ids,
    const int* __restrict__ col_ids, bf* __restrict__ tabp,
    bf* __restrict__ colp) {
  // grid = 4608; 4608 % 8 == 0 -> simple chunked bijection
  int swz = (blockIdx.x & 7) * 576 + (blockIdx.x >> 3);
  int w = threadIdx.x >> 6, l = threadIdx.x & 63;
  int row = swz * 4 + w;
  int b = row / (Tc + Cc), r = row % (Tc + Cc);
  const int* ids;
  bf* outp;
  if (r < Tc) {
    ids = tab_ids + ((size_t)b * Tc + r) * Lc;
    outp = tabp + ((size_t)b * Tc + r) * Dc;
  } else {
    int c = r - Tc;
    ids = col_ids + ((size_t)b * Cc + c) * Lc;
    outp = colp + ((size_t)b * Cc + c) * Dc;
  }
  float4 a0 = {0, 0, 0, 0}, a1 = {0, 0, 0, 0}, a2 = {0, 0, 0, 0};
#pragma unroll
  for (int tix = 0; tix < Lc; ++tix) {
    const float4* p =
        reinterpret_cast<const float4*>(seq + ((size_t)b * Sc + ids[tix]) * Dc);
    float4 v0 = p[l], v1 = p[l + 64], v2 = p[l + 128];
    a0.x += v0.x; a0.y += v0.y; a0.z += v0.z; a0.w += v0.w;
    a1.x += v1.x; a1.y += v1.y; a1.z += v1.z; a1.w += v1.w;
    a2.x += v2.x; a2.y += v2.y; a2.z += v2.z; a2.w += v2.w;
  }
  ushort4* ob = reinterpret_cast<ushort4*>(outp);
  ob[l] = make_ushort4(f2bf(a0.x), f2bf(a0.y), f2bf(a0.z), f2bf(a0.w));
  ob[l + 64] = make_ushort4(f2bf(a1.x), f2bf(a1.y), f2bf(a1.z), f2bf(a1.w));
  ob[l + 128] = make_ushort4(f2bf(a2.x), f2bf(a2.y), f2bf(a2.z), f2bf(a2.w));
}

// ---------------------------------------------------------------------------
// 2) bf16 MFMA GEMM, BK=64 (halved barrier count vs BK=32 m97 clone):
//    out = act(A[M,K] @ Bt[N,K]^T + bias). 128x128 tile, 4 waves, 4x4
//    16x16x32 fragments x 2 k-subtiles, global_load_lds width-16 staging.
//    OUTMODE: 0 = bf16 out, 1 = f32 out, 2 = both,
//             3 = fused 2-wide head: atomicAdd(leaky(v) @ w2) into outd.
// ---------------------------------------------------------------------------
template <int OUTMODE, bool LEAKY, int LOG2RPB>
__global__ __launch_bounds__(256) void gemm_bf16(
    const bf* __restrict__ A, const bf* __restrict__ Bt,
    const float* __restrict__ bias, bf* __restrict__ Obf,
    float* __restrict__ Of32, const float* __restrict__ w2,
    float* __restrict__ outd, int out_base, int M, int N, int K) {
  constexpr int BM = 128, BN = 128, BK = 64;
  __shared__ bf As[BM * BK];
  __shared__ bf Bs[BN * BK];
  int tid = threadIdx.x;
  int row0 = blockIdx.y * BM, col0 = blockIdx.x * BN;
  int w = tid >> 6, l = tid & 63;
  int wr = (w >> 1) * 64, wc = (w & 1) * 64;
  f32x4 acc[4][4];
#pragma unroll
  for (int m = 0; m < 4; ++m)
#pragma unroll
    for (int n = 0; n < 4; ++n) acc[m][n] = f32x4{0.f, 0.f, 0.f, 0.f};

  // staging: call c covers rows [c*32, c*32+32); thread -> (row, kk)
  int srow = tid >> 3, skk = (tid & 7) * 8;
  const bf* gA = A + (size_t)(row0 + srow) * K + skk;
  const bf* gB = Bt + (size_t)(col0 + srow) * K + skk;
  char* lA = (char*)As + tid * 16;
  char* lB = (char*)Bs + tid * 16;
  int lr = l & 15, lk = (l >> 4) * 8;

  for (int k0 = 0; k0 < K; k0 += BK) {
#pragma unroll
    for (int c = 0; c < 4; ++c) {
      GLDS16(gA + k0 + (size_t)c * 32 * K, lA + c * 4096);
      GLDS16(gB + k0 + (size_t)c * 32 * K, lB + c * 4096);
    }
    __syncthreads();  // drains vmcnt + lgkm before use
    bf16x8 af[2][4], bfr[2][4];
#pragma unroll
    for (int ks = 0; ks < 2; ++ks) {
#pragma unroll
      for (int m = 0; m < 4; ++m)
        af[ks][m] = *reinterpret_cast<const bf16x8*>(
            &As[(wr + m * 16 + lr) * BK + ks * 32 + lk]);
#pragma unroll
      for (int n = 0; n < 4; ++n)
        bfr[ks][n] = *reinterpret_cast<const bf16x8*>(
            &Bs[(wc + n * 16 + lr) * BK + ks * 32 + lk]);
    }
#pragma unroll
    for (int ks = 0; ks < 2; ++ks)
#pragma unroll
      for (int m = 0; m < 4; ++m)
#pragma unroll
        for (int n = 0; n < 4; ++n)
          acc[m][n] = __builtin_amdgcn_mfma_f32_16x16x32_bf16(
              af[ks][m], bfr[ks][n], acc[m][n], 0, 0, 0);
    __syncthreads();
  }

  // C/D layout: col = lane&15, row = (lane>>4)*4 + reg
  int colI = l & 15, rowb = (l >> 4) * 4;
  if (OUTMODE == 3) {
    float w20[4], w21[4], bv[4];
#pragma unroll
    for (int n = 0; n < 4; ++n) {
      int c = col0 + wc + n * 16 + colI;
      w20[n] = w2[c * 2];
      w21[n] = w2[c * 2 + 1];
      bv[n] = bias[c];
    }
    float p0[4][4], p1[4][4];
#pragma unroll
    for (int m = 0; m < 4; ++m)
#pragma unroll
      for (int j = 0; j < 4; ++j) { p0[m][j] = 0.f; p1[m][j] = 0.f; }
#pragma unroll
    for (int m = 0; m < 4; ++m)
#pragma unroll
      for (int n = 0; n < 4; ++n)
#pragma unroll
        for (int j = 0; j < 4; ++j) {
          float v = acc[m][n][j] + bv[n];
          v = v >= 0.f ? v : 0.01f * v;  // leaky always on for heads
          p0[m][j] += v * w20[n];
          p1[m][j] += v * w21[n];
        }
    // reduce across the 16 colI lanes
#pragma unroll
    for (int m = 0; m < 4; ++m)
#pragma unroll
      for (int j = 0; j < 4; ++j) {
#pragma unroll
        for (int msk = 1; msk <= 8; msk <<= 1) {
          p0[m][j] += __shfl_xor(p0[m][j], msk);
          p1[m][j] += __shfl_xor(p1[m][j], msk);
        }
      }
    if (colI == 0) {
#pragma unroll
      for (int m = 0; m < 4; ++m)
#pragma unroll
        for (int j = 0; j < 4; ++j) {
          int grow = row0 + wr + m * 16 + rowb + j;
          int bb = grow >> LOG2RPB;
          int rr = grow & ((1 << LOG2RPB) - 1);
          int orow = bb * (Tc + Cc) + out_base + rr;
          atomicAdd(&outd[(size_t)orow * 2], p0[m][j]);
          atomicAdd(&outd[(size_t)orow * 2 + 1], p1[m][j]);
        }
    }
    return;
  }
#pragma unroll
  for (int m = 0; m < 4; ++m) {
#pragma unroll
    for (int n = 0; n < 4; ++n) {
      int c = col0 + wc + n * 16 + colI;
      float bv = bias ? bias[c] : 0.f;
#pragma unroll
      for (int j = 0; j < 4; ++j) {
        int r = row0 + wr + m * 16 + rowb + j;
        float v = acc[m][n][j] + bv;
        if (LEAKY) v = v >= 0.f ? v : 0.01f * v;
        if (OUTMODE == 0 || OUTMODE == 2)
          Obf[(size_t)r * N + c] = __float2bfloat16(v);
        if (OUTMODE == 1 || OUTMODE == 2) Of32[(size_t)r * N + c] = v;
      }
    }
  }
}

// ---------------------------------------------------------------------------
// 3) Bucket columns by table (CSR): one block per batch.
// ---------------------------------------------------------------------------
__global__ __launch_bounds__(256) void bucket_kernel(
    const int* __restrict__ t_of_c, int* __restrict__ col_sorted,
    int* __restrict__ offs) {
  int b = blockIdx.x, tid = threadIdx.x;
  __shared__ int cnt[Tc];
  __shared__ int cur[Tc + 1];
  if (tid < Tc) cnt[tid] = 0;
  __syncthreads();
  for (int c = tid; c < Cc; c += 256) atomicAdd(&cnt[t_of_c[b * Cc + c]], 1);
  __syncthreads();
  if (tid == 0) {
    int off = 0;
    for (int t = 0; t < Tc; ++t) {
      cur[t] = off;
      off += cnt[t];
    }
    cur[Tc] = off;
  }
  __syncthreads();
  if (tid <= Tc) offs[b * (Tc + 1) + tid] = cur[tid];
  __syncthreads();
  for (int c = tid; c < Cc; c += 256) {
    int t = t_of_c[b * Cc + c];
    int pos = atomicAdd(&cur[t], 1);
    col_sorted[b * Cc + pos] = c;
  }
}

// ---------------------------------------------------------------------------
// 4) Masked cross-attention, lane-group parallel + vectorized bf16 loads.
//    One block per (b,t). 8 heads x 32 lanes; within a head unit: 4 column
//    groups x 8 lanes; each lane owns 12 head dims (3 x ushort4).
//    n==0 -> uniform over all C (reference's all -1e9 softmax).
// ---------------------------------------------------------------------------
__global__ __launch_bounds__(256) void attn_kernel(
    const bf* __restrict__ q, const bf* __restrict__ kv,
    const int* __restrict__ col_sorted, const int* __restrict__ offs,
    bf* __restrict__ ctx) {
  int b = blockIdx.x / Tc;
  int t = blockIdx.x % Tc;
  __shared__ float pbuf[Hc][Cc];
  __shared__ float den[Hc];
  __shared__ int cols_s[Cc];
  int tid = threadIdx.x;
  int o0 = offs[b * (Tc + 1) + t];
  int n = offs[b * (Tc + 1) + t + 1] - o0;
  for (int i = tid; i < n; i += 256)
    cols_s[i] = col_sorted[(size_t)b * Cc + o0 + i];
  __syncthreads();
  int h = tid >> 5, l32 = tid & 31, g = l32 >> 3, i8 = l32 & 7;
  const float scale = 0.10206207261596577f;  // 1/sqrt(96)
  // q fragment (12 dims) in registers
  float q12[12];
  {
    const ushort* qp = (const ushort*)q + ((size_t)b * Tc + t) * Dc + h * DHc + i8 * 12;
    ushort4 u0 = *(const ushort4*)(qp);
    ushort4 u1 = *(const ushort4*)(qp + 4);
    ushort4 u2 = *(const ushort4*)(qp + 8);
    q12[0] = us2f(u0.x); q12[1] = us2f(u0.y); q12[2] = us2f(u0.z); q12[3] = us2f(u0.w);
    q12[4] = us2f(u1.x); q12[5] = us2f(u1.y); q12[6] = us2f(u1.z); q12[7] = us2f(u1.w);
    q12[8] = us2f(u2.x); q12[9] = us2f(u2.y); q12[10] = us2f(u2.z); q12[11] = us2f(u2.w);
  }
  if (n > 0) {
    for (int jb = 0; jb < n; jb += 4) {
      int j = jb + g;
      float s = 0.f;
      if (j < n) {
        const ushort* kp =
            (const ushort*)kv + ((size_t)b * Cc + cols_s[j]) * 1536 + h * DHc + i8 * 12;
        ushort4 u0 = *(const ushort4*)(kp);
        ushort4 u1 = *(const ushort4*)(kp + 4);
        ushort4 u2 = *(const ushort4*)(kp + 8);
        s += q12[0] * us2f(u0.x) + q12[1] * us2f(u0.y) + q12[2] * us2f(u0.z) +
             q12[3] * us2f(u0.w);
        s += q12[4] * us2f(u1.x) + q12[5] * us2f(u1.y) + q12[6] * us2f(u1.z) +
             q12[7] * us2f(u1.w);
        s += q12[8] * us2f(u2.x) + q12[9] * us2f(u2.y) + q12[10] * us2f(u2.z) +
             q12[11] * us2f(u2.w);
      }
      s += __shfl_xor(s, 1);
      s += __shfl_xor(s, 2);
      s += __shfl_xor(s, 4);
      if (j < n && i8 == 0) pbuf[h][j] = s * scale;
    }
  }
  __syncthreads();
  if (n > 0) {
    float lmax = -3.0e38f;
    for (int j = l32; j < n; j += 32) lmax = fmaxf(lmax, pbuf[h][j]);
#pragma unroll
    for (int m = 16; m >= 1; m >>= 1) lmax = fmaxf(lmax, __shfl_xor(lmax, m));
    float lsum = 0.f;
    for (int j = l32; j < n; j += 32) {
      float e = __expf(pbuf[h][j] - lmax);
      pbuf[h][j] = e;
      lsum += e;
    }
#pragma unroll
    for (int m = 16; m >= 1; m >>= 1) lsum += __shfl_xor(lsum, m);
    if (l32 == 0) den[h] = lsum;
  } else if (l32 == 0) {
    den[h] = (float)Cc;
  }
  __syncthreads();
  int ncols = n > 0 ? n : Cc;
  float a12[12];
#pragma unroll
  for (int d = 0; d < 12; ++d) a12[d] = 0.f;
  for (int jb = 0; jb < ncols; jb += 4) {
    int j = jb + g;
    if (j < ncols) {
      int cj = n > 0 ? cols_s[j] : j;
      float pw = n > 0 ? pbuf[h][j] : 1.f;
      const ushort* vp =
          (const ushort*)kv + ((size_t)b * Cc + cj) * 1536 + 768 + h * DHc + i8 * 12;
      ushort4 u0 = *(const ushort4*)(vp);
      ushort4 u1 = *(const ushort4*)(vp + 4);
      ushort4 u2 = *(const ushort4*)(vp + 8);
      a12[0] += pw * us2f(u0.x); a12[1] += pw * us2f(u0.y);
      a12[2] += pw * us2f(u0.z); a12[3] += pw * us2f(u0.w);
      a12[4] += pw * us2f(u1.x); a12[5] += pw * us2f(u1.y);
      a12[6] += pw * us2f(u1.z); a12[7] += pw * us2f(u1.w);
      a12[8] += pw * us2f(u2.x); a12[9] += pw * us2f(u2.y);
      a12[10] += pw * us2f(u2.z); a12[11] += pw * us2f(u2.w);
    }
  }
#pragma unroll
  for (int d = 0; d < 12; ++d) {
    a12[d] += __shfl_xor(a12[d], 8);
    a12[d] += __shfl_xor(a12[d], 16);
  }
  float inv = 1.0f / den[h];
  if (g == 0) {
    ushort* cp = (ushort*)ctx + ((size_t)b * Tc + t) * Dc + h * DHc + i8 * 12;
    ushort4 o0 = make_ushort4(f2bf(a12[0] * inv), f2bf(a12[1] * inv),
                              f2bf(a12[2] * inv), f2bf(a12[3] * inv));
    ushort4 o1 = make_ushort4(f2bf(a12[4] * inv), f2bf(a12[5] * inv),
                              f2bf(a12[6] * inv), f2bf(a12[7] * inv));
    ushort4 o2 = make_ushort4(f2bf(a12[8] * inv), f2bf(a12[9] * inv),
                              f2bf(a12[10] * inv), f2bf(a12[11] * inv));
    *(ushort4*)(cp) = o0;
    *(ushort4*)(cp + 4) = o1;
    *(ushort4*)(cp + 8) = o2;
  }
}

// ---------------------------------------------------------------------------
// 5) residual add + L2 normalize (f32 in, bf16 out)
// ---------------------------------------------------------------------------
__global__ __launch_bounds__(256) void addnorm_kernel(
    const float* __restrict__ tab, const float* __restrict__ proj,
    bf* __restrict__ tabn) {
  int row = blockIdx.x;
  int tid = threadIdx.x;
  size_t base = (size_t)row * Dc;
  float x0 = tab[base + tid] + proj[base + tid];
  float x1 = tab[base + tid + 256] + proj[base + tid + 256];
  float x2 = tab[base + tid + 512] + proj[base + tid + 512];
  float ss = x0 * x0 + x1 * x1 + x2 * x2;
#pragma unroll
  for (int m = 32; m >= 1; m >>= 1) ss += __shfl_xor(ss, m);
  __shared__ float red[4];
  int wave = tid >> 6, lane = tid & 63;
  if (lane == 0) red[wave] = ss;
  __syncthreads();
  float total = red[0] + red[1] + red[2] + red[3];
  float sc = 1.0f / fmaxf(sqrtf(total), 1e-12f);
  tabn[base + tid] = __float2bfloat16(x0 * sc);
  tabn[base + tid + 256] = __float2bfloat16(x1 * sc);
  tabn[base + tid + 512] = __float2bfloat16(x2 * sc);
}

// ---------------------------------------------------------------------------
extern "C" void kernel_launch(void* const* d_in, const int* in_sizes, int n_in,
                              void* d_out, int out_size, void* d_ws,
                              size_t ws_size, hipStream_t stream) {
  const float* seq = (const float*)d_in[0];
  const int* tab_ids = (const int*)d_in[1];
  const int* col_ids = (const int*)d_in[2];
  const int* t_of_c = (const int*)d_in[3];
  const float* W_tab_pool = (const float*)d_in[4];
  const float* b_tab_pool = (const float*)d_in[5];
  const float* W_col_pool = (const float*)d_in[6];
  const float* b_col_pool = (const float*)d_in[7];
  const float* in_proj_w = (const float*)d_in[8];
  const float* in_proj_b = (const float*)d_in[9];
  const float* out_proj_w = (const float*)d_in[10];
  const float* out_proj_b = (const float*)d_in[11];
  const float* W_t1 = (const float*)d_in[12];
  const float* b_t1 = (const float*)d_in[13];
  const float* W_t2 = (const float*)d_in[14];
  const float* b_t2 = (const float*)d_in[15];
  const float* W_c1 = (const float*)d_in[16];
  const float* b_c1 = (const float*)d_in[17];
  const float* W_c2 = (const float*)d_in[18];
  const float* b_c2 = (const float*)d_in[19];
  float* out = (float*)d_out;

  char* p = (char*)d_ws;
  auto alloc = [&](size_t bytes) -> char* {
    char* r = p;
    p += (bytes + 255) & ~(size_t)255;
    return r;
  };
  const size_t nBT = (size_t)Bc * Tc;   // 2048
  const size_t nBC = (size_t)Bc * Cc;   // 16384
  bf* tabp = (bf*)alloc(nBT * Dc * 2);
  bf* colp = (bf*)alloc(nBC * Dc * 2);
  bf* tabb_bf = (bf*)alloc(nBT * Dc * 2);
  float* tabb_f = (float*)alloc(nBT * Dc * 4);
  bf* colb = (bf*)alloc(nBC * Dc * 2);
  bf* qb = (bf*)alloc(nBT * Dc * 2);
  bf* kvb = (bf*)alloc(nBC * 1536 * 2);
  bf* ctxb = (bf*)alloc(nBT * Dc * 2);
  float* projb = (float*)alloc(nBT * Dc * 4);
  bf* tabn = (bf*)alloc(nBT * Dc * 2);
  bf* wtab_t = (bf*)alloc((size_t)Dc * Dc * 2);
  bf* wcol_t = (bf*)alloc((size_t)Dc * Dc * 2);
  bf* winproj = (bf*)alloc((size_t)3 * Dc * Dc * 2);
  bf* woutproj = (bf*)alloc((size_t)Dc * Dc * 2);
  bf* wt1_t = (bf*)alloc((size_t)256 * Dc * 2);
  bf* wc1_t = (bf*)alloc((size_t)256 * Dc * 2);
  int* col_sorted = (int*)alloc(nBC * 4);
  int* offs = (int*)alloc((size_t)Bc * (Tc + 1) * 4);

  // 0) all weight conversions + d_out bias init, one launch
  prep_kernel<<<3984, 256, 0, stream>>>(W_tab_pool, W_col_pool, W_t1, W_c1,
                                        in_proj_w, out_proj_w, b_t2, b_c2,
                                        wtab_t, wcol_t, wt1_t, wc1_t, winproj,
                                        woutproj, out);
  bucket_kernel<<<Bc, 256, 0, stream>>>(t_of_c, col_sorted, offs);
  pool_kernel<<<Bc * (Tc + Cc) / 4, 256, 0, stream>>>(seq, tab_ids, col_ids,
                                                      tabp, colp);
  // pool linears (+leaky)
  gemm_bf16<2, true, 0><<<dim3(Dc / 128, nBT / 128), 256, 0, stream>>>(
      tabp, wtab_t, b_tab_pool, tabb_bf, tabb_f, nullptr, nullptr, 0, nBT, Dc,
      Dc);
  gemm_bf16<0, true, 0><<<dim3(Dc / 128, nBC / 128), 256, 0, stream>>>(
      colp, wcol_t, b_col_pool, colb, nullptr, nullptr, nullptr, 0, nBC, Dc,
      Dc);
  // q and fused kv projections
  gemm_bf16<0, false, 0><<<dim3(Dc / 128, nBT / 128), 256, 0, stream>>>(
      tabb_bf, winproj, in_proj_b, qb, nullptr, nullptr, nullptr, 0, nBT, Dc,
      Dc);
  gemm_bf16<0, false, 0><<<dim3(1536 / 128, nBC / 128), 256, 0, stream>>>(
      colb, winproj + (size_t)Dc * Dc, in_proj_b + Dc, kvb, nullptr, nullptr,
      nullptr, 0, nBC, 1536, Dc);
  // attention
  attn_kernel<<<Bc * Tc, 256, 0, stream>>>(qb, kvb, col_sorted, offs, ctxb);
  // out projection (f32) + residual + L2 norm
  gemm_bf16<1, false, 0><<<dim3(Dc / 128, nBT / 128), 256, 0, stream>>>(
      ctxb, woutproj, out_proj_b, nullptr, projb, nullptr, nullptr, 0, nBT, Dc,
      Dc);
  addnorm_kernel<<<nBT, 256, 0, stream>>>(tabb_f, projb, tabn);
  // heads, final 2-wide projection fused via atomics into bias-inited out
  gemm_bf16<3, true, 6><<<dim3(256 / 128, nBT / 128), 256, 0, stream>>>(
      tabn, wt1_t, b_t1, nullptr, nullptr, W_t2, out, 0, nBT, 256, Dc);
  gemm_bf16<3, true, 9><<<dim3(256 / 128, nBC / 128), 256, 0, stream>>>(
      colb, wc1_t, b_c1, nullptr, nullptr, W_c2, out, Tc, nBC, 256, Dc);
}

// Round 4
// 572.098 us; speedup vs baseline: 2.6954x; 1.0551x over previous
//
#include <hip/hip_runtime.h>
#include <hip/hip_bf16.h>

constexpr int Bc = 32;    // batch
constexpr int Sc = 2048;  // sequence length
constexpr int Tc = 64;    // tables
constexpr int Cc = 512;   // columns
constexpr int Lc = 16;    // tokens per span
constexpr int Dc = 768;   // hidden
constexpr int Hc = 8;     // heads
constexpr int DHc = 96;   // head dim

typedef __attribute__((ext_vector_type(4))) float f32x4;
typedef __attribute__((ext_vector_type(8))) short bf16x8;  // 8 bf16 in 4 VGPRs
typedef __hip_bfloat16 bf;

__device__ inline unsigned short f2bf(float f) {
  __hip_bfloat16 h = __float2bfloat16(f);
  return *reinterpret_cast<unsigned short*>(&h);
}
__device__ inline float us2f(unsigned short u) {
  return __uint_as_float(((unsigned)u) << 16);
}

#define GLDS16(gp, lp)                                                        \
  __builtin_amdgcn_global_load_lds(                                           \
      (const __attribute__((address_space(1))) void*)(gp),                    \
      (__attribute__((address_space(3))) void*)(lp), 16, 0, 0)

// ---------------------------------------------------------------------------
// 0) Fused prep: weight conversions/transposes, d_out bias-init, seq f32->bf16
//    conversion, and column bucketing (CSR) — ONE launch, region-dispatched.
//    [0,576)        W_tab_pool 768x768 [K][N] -> bf16 [N][K]
//    [576,1152)     W_col_pool  "
//    [1152,1344)    W_t1 768x256 -> bf16 [256][768]
//    [1344,1536)    W_c1 768x256 -> bf16 [256][768]
//    [1536,3264)    in_proj  f32->bf16 (already [N][K])
//    [3264,3840)    out_proj f32->bf16
//    [3840,3984)    d_out init with head biases (atomic targets)
//    [3984,28560)   seq f32 -> bf16 (2 float4 / thread)
//    [28560,28592)  bucket (one block per batch)
// ---------------------------------------------------------------------------
__device__ inline void transpose32(const float* __restrict__ in,
                                   bf* __restrict__ outp, int K, int N,
                                   int ti, float (*t)[33]) {
  int nx = N >> 5;
  int bx = (ti % nx) * 32, by = (ti / nx) * 32;
  int x = threadIdx.x & 31, y = threadIdx.x >> 5;  // 32 x 8
#pragma unroll
  for (int i = 0; i < 32; i += 8)
    t[y + i][x] = in[(size_t)(by + y + i) * N + bx + x];
  __syncthreads();
#pragma unroll
  for (int i = 0; i < 32; i += 8)
    outp[(size_t)(bx + y + i) * K + by + x] = __float2bfloat16(t[x][y + i]);
}

__global__ __launch_bounds__(256) void prep_kernel(
    const float* __restrict__ W_tab_pool, const float* __restrict__ W_col_pool,
    const float* __restrict__ W_t1, const float* __restrict__ W_c1,
    const float* __restrict__ in_proj_w, const float* __restrict__ out_proj_w,
    const float* __restrict__ b_t2, const float* __restrict__ b_c2,
    const float* __restrict__ seq, const int* __restrict__ t_of_c,
    bf* __restrict__ wtab_t, bf* __restrict__ wcol_t, bf* __restrict__ wt1_t,
    bf* __restrict__ wc1_t, bf* __restrict__ winproj, bf* __restrict__ woutproj,
    float* __restrict__ outd, ushort* __restrict__ seqb,
    int* __restrict__ col_sorted, int* __restrict__ offs) {
  __shared__ float t[32][33];
  __shared__ int cnt[Tc];
  __shared__ int cur[Tc + 1];
  int blk = blockIdx.x, tid = threadIdx.x;
  if (blk < 576) {
    transpose32(W_tab_pool, wtab_t, Dc, Dc, blk, t);
  } else if (blk < 1152) {
    transpose32(W_col_pool, wcol_t, Dc, Dc, blk - 576, t);
  } else if (blk < 1344) {
    transpose32(W_t1, wt1_t, Dc, 256, blk - 1152, t);
  } else if (blk < 1536) {
    transpose32(W_c1, wc1_t, Dc, 256, blk - 1344, t);
  } else if (blk < 3264) {
    int i = (blk - 1536) * 256 + tid;
    float4 v = reinterpret_cast<const float4*>(in_proj_w)[i];
    reinterpret_cast<ushort4*>(winproj)[i] =
        make_ushort4(f2bf(v.x), f2bf(v.y), f2bf(v.z), f2bf(v.w));
  } else if (blk < 3840) {
    int i = (blk - 3264) * 256 + tid;
    float4 v = reinterpret_cast<const float4*>(out_proj_w)[i];
    reinterpret_cast<ushort4*>(woutproj)[i] =
        make_ushort4(f2bf(v.x), f2bf(v.y), f2bf(v.z), f2bf(v.w));
  } else if (blk < 3984) {
    int e = (blk - 3840) * 256 + tid;  // < 36864
    int i = e & 1;
    int r = (e >> 1) % (Tc + Cc);
    outd[e] = (r < Tc) ? b_t2[i] : b_c2[i];
  } else if (blk < 28560) {
    int i0 = (blk - 3984) * 512 + tid;
    const float4* s4 = reinterpret_cast<const float4*>(seq);
    ushort4* o4 = reinterpret_cast<ushort4*>(seqb);
    float4 v = s4[i0];
    o4[i0] = make_ushort4(f2bf(v.x), f2bf(v.y), f2bf(v.z), f2bf(v.w));
    float4 v2 = s4[i0 + 256];
    o4[i0 + 256] = make_ushort4(f2bf(v2.x), f2bf(v2.y), f2bf(v2.z), f2bf(v2.w));
  } else {
    // bucket: one block per batch
    int b = blk - 28560;
    if (tid < Tc) cnt[tid] = 0;
    __syncthreads();
    for (int c = tid; c < Cc; c += 256) atomicAdd(&cnt[t_of_c[b * Cc + c]], 1);
    __syncthreads();
    if (tid == 0) {
      int off = 0;
      for (int tt = 0; tt < Tc; ++tt) {
        cur[tt] = off;
        off += cnt[tt];
      }
      cur[Tc] = off;
    }
    __syncthreads();
    if (tid <= Tc) offs[b * (Tc + 1) + tid] = cur[tid];
    __syncthreads();
    for (int c = tid; c < Cc; c += 256) {
      int tt = t_of_c[b * Cc + c];
      int pos = atomicAdd(&cur[tt], 1);
      col_sorted[b * Cc + pos] = c;
    }
  }
}

// ---------------------------------------------------------------------------
// 1) Ragged gather + sum pooling from bf16 seq. One wave per output row,
//    XCD-chunked swizzle (each XCD streams a contiguous set of batches).
// ---------------------------------------------------------------------------
__global__ __launch_bounds__(256) void pool_kernel(
    const ushort* __restrict__ seqb, const int* __restrict__ tab_ids,
    const int* __restrict__ col_ids, ushort* __restrict__ tabp,
    ushort* __restrict__ colp) {
  // grid = 4608; 4608 % 8 == 0 -> chunked bijection
  int swz = (blockIdx.x & 7) * 576 + (blockIdx.x >> 3);
  int w = threadIdx.x >> 6, l = threadIdx.x & 63;
  int row = swz * 4 + w;
  int b = row / (Tc + Cc), r = row % (Tc + Cc);
  const int* ids;
  ushort* outp;
  if (r < Tc) {
    ids = tab_ids + ((size_t)b * Tc + r) * Lc;
    outp = tabp + ((size_t)b * Tc + r) * Dc;
  } else {
    int c = r - Tc;
    ids = col_ids + ((size_t)b * Cc + c) * Lc;
    outp = colp + ((size_t)b * Cc + c) * Dc;
  }
  float a0[4] = {0, 0, 0, 0}, a1[4] = {0, 0, 0, 0}, a2[4] = {0, 0, 0, 0};
#pragma unroll
  for (int tix = 0; tix < Lc; ++tix) {
    const ushort4* p =
        reinterpret_cast<const ushort4*>(seqb + ((size_t)b * Sc + ids[tix]) * Dc);
    ushort4 u0 = p[l], u1 = p[l + 64], u2 = p[l + 128];
    a0[0] += us2f(u0.x); a0[1] += us2f(u0.y); a0[2] += us2f(u0.z); a0[3] += us2f(u0.w);
    a1[0] += us2f(u1.x); a1[1] += us2f(u1.y); a1[2] += us2f(u1.z); a1[3] += us2f(u1.w);
    a2[0] += us2f(u2.x); a2[1] += us2f(u2.y); a2[2] += us2f(u2.z); a2[3] += us2f(u2.w);
  }
  ushort4* ob = reinterpret_cast<ushort4*>(outp);
  ob[l] = make_ushort4(f2bf(a0[0]), f2bf(a0[1]), f2bf(a0[2]), f2bf(a0[3]));
  ob[l + 64] = make_ushort4(f2bf(a1[0]), f2bf(a1[1]), f2bf(a1[2]), f2bf(a1[3]));
  ob[l + 128] = make_ushort4(f2bf(a2[0]), f2bf(a2[1]), f2bf(a2[2]), f2bf(a2[3]));
}

// ---------------------------------------------------------------------------
// 2) bf16 MFMA GEMM core (m97 structure, BK=64, K=768 fixed):
//    out = act(A[M,768] @ Bt[N,768]^T + bias). 128x128 tile, 4 waves, 4x4
//    16x16x32 fragments x 2 k-subtiles, global_load_lds width-16 staging.
//    outmode: 0 = bf16 out, 1 = f32 out, 2 = both,
//             3 = fused 2-wide head: atomicAdd(leaky(v) @ w2) into outd.
// ---------------------------------------------------------------------------
__device__ __forceinline__ void gemm_core(
    const bf* __restrict__ A, const bf* __restrict__ Bt,
    const float* __restrict__ bias, bf* __restrict__ Obf,
    float* __restrict__ Of32, const float* __restrict__ w2,
    float* __restrict__ outd, int out_base, int log2rpb, int bx, int by, int N,
    int leaky, int outmode) {
  constexpr int BM = 128, BN = 128, BK = 64, K = Dc;
  __shared__ bf As[BM * BK];
  __shared__ bf Bs[BN * BK];
  int tid = threadIdx.x;
  int row0 = by * BM, col0 = bx * BN;
  int w = tid >> 6, l = tid & 63;
  int wr = (w >> 1) * 64, wc = (w & 1) * 64;
  f32x4 acc[4][4];
#pragma unroll
  for (int m = 0; m < 4; ++m)
#pragma unroll
    for (int n = 0; n < 4; ++n) acc[m][n] = f32x4{0.f, 0.f, 0.f, 0.f};

  int srow = tid >> 3, skk = (tid & 7) * 8;
  const bf* gA = A + (size_t)(row0 + srow) * K + skk;
  const bf* gB = Bt + (size_t)(col0 + srow) * K + skk;
  char* lA = (char*)As + tid * 16;
  char* lB = (char*)Bs + tid * 16;
  int lr = l & 15, lk = (l >> 4) * 8;

  for (int k0 = 0; k0 < K; k0 += BK) {
#pragma unroll
    for (int c = 0; c < 4; ++c) {
      GLDS16(gA + k0 + (size_t)c * 32 * K, lA + c * 4096);
      GLDS16(gB + k0 + (size_t)c * 32 * K, lB + c * 4096);
    }
    __syncthreads();
    bf16x8 af[2][4], bfr[2][4];
#pragma unroll
    for (int ks = 0; ks < 2; ++ks) {
#pragma unroll
      for (int m = 0; m < 4; ++m)
        af[ks][m] = *reinterpret_cast<const bf16x8*>(
            &As[(wr + m * 16 + lr) * BK + ks * 32 + lk]);
#pragma unroll
      for (int n = 0; n < 4; ++n)
        bfr[ks][n] = *reinterpret_cast<const bf16x8*>(
            &Bs[(wc + n * 16 + lr) * BK + ks * 32 + lk]);
    }
#pragma unroll
    for (int ks = 0; ks < 2; ++ks)
#pragma unroll
      for (int m = 0; m < 4; ++m)
#pragma unroll
        for (int n = 0; n < 4; ++n)
          acc[m][n] = __builtin_amdgcn_mfma_f32_16x16x32_bf16(
              af[ks][m], bfr[ks][n], acc[m][n], 0, 0, 0);
    __syncthreads();
  }

  // C/D layout: col = lane&15, row = (lane>>4)*4 + reg
  int colI = l & 15, rowb = (l >> 4) * 4;
  if (outmode == 3) {
    float w20[4], w21[4], bv[4];
#pragma unroll
    for (int n = 0; n < 4; ++n) {
      int c = col0 + wc + n * 16 + colI;
      w20[n] = w2[c * 2];
      w21[n] = w2[c * 2 + 1];
      bv[n] = bias[c];
    }
    float p0[4][4], p1[4][4];
#pragma unroll
    for (int m = 0; m < 4; ++m)
#pragma unroll
      for (int j = 0; j < 4; ++j) { p0[m][j] = 0.f; p1[m][j] = 0.f; }
#pragma unroll
    for (int m = 0; m < 4; ++m)
#pragma unroll
      for (int n = 0; n < 4; ++n)
#pragma unroll
        for (int j = 0; j < 4; ++j) {
          float v = acc[m][n][j] + bv[n];
          v = v >= 0.f ? v : 0.01f * v;  // leaky always on for heads
          p0[m][j] += v * w20[n];
          p1[m][j] += v * w21[n];
        }
#pragma unroll
    for (int m = 0; m < 4; ++m)
#pragma unroll
      for (int j = 0; j < 4; ++j) {
#pragma unroll
        for (int msk = 1; msk <= 8; msk <<= 1) {
          p0[m][j] += __shfl_xor(p0[m][j], msk);
          p1[m][j] += __shfl_xor(p1[m][j], msk);
        }
      }
    if (colI == 0) {
#pragma unroll
      for (int m = 0; m < 4; ++m)
#pragma unroll
        for (int j = 0; j < 4; ++j) {
          int grow = row0 + wr + m * 16 + rowb + j;
          int bb = grow >> log2rpb;
          int rr = grow & ((1 << log2rpb) - 1);
          int orow = bb * (Tc + Cc) + out_base + rr;
          atomicAdd(&outd[(size_t)orow * 2], p0[m][j]);
          atomicAdd(&outd[(size_t)orow * 2 + 1], p1[m][j]);
        }
    }
    return;
  }
#pragma unroll
  for (int m = 0; m < 4; ++m) {
#pragma unroll
    for (int n = 0; n < 4; ++n) {
      int c = col0 + wc + n * 16 + colI;
      float bv = bias ? bias[c] : 0.f;
#pragma unroll
      for (int j = 0; j < 4; ++j) {
        int r = row0 + wr + m * 16 + rowb + j;
        float v = acc[m][n][j] + bv;
        if (leaky) v = v >= 0.f ? v : 0.01f * v;
        if (outmode == 0 || outmode == 2) Obf[(size_t)r * N + c] = __float2bfloat16(v);
        if (outmode == 1 || outmode == 2) Of32[(size_t)r * N + c] = v;
      }
    }
  }
}

// Combined launch A: tab pool-linear (96 blocks) + col pool-linear (768).
__global__ __launch_bounds__(256) void gemm_pools(
    const bf* __restrict__ tabp, const bf* __restrict__ colp,
    const bf* __restrict__ wtab_t, const bf* __restrict__ wcol_t,
    const float* __restrict__ b_tab, const float* __restrict__ b_col,
    bf* __restrict__ tabb_bf, float* __restrict__ tabb_f,
    bf* __restrict__ colb) {
  // grid 864 = 8 * 108 -> XCD-chunked
  int id = (blockIdx.x & 7) * 108 + (blockIdx.x >> 3);
  if (id < 96) {
    gemm_core(tabp, wtab_t, b_tab, tabb_bf, tabb_f, nullptr, nullptr, 0, 0,
              id % 6, id / 6, Dc, 1, 2);
  } else {
    int r = id - 96;
    gemm_core(colp, wcol_t, b_col, colb, nullptr, nullptr, nullptr, 0, 0,
              r % 6, r / 6, Dc, 1, 0);
  }
}

// Combined launch B: q (96) + fused kv (1536) + c1 head (256).
__global__ __launch_bounds__(256) void gemm_qkvc(
    const bf* __restrict__ tabb_bf, const bf* __restrict__ colb,
    const bf* __restrict__ winproj, const float* __restrict__ in_proj_b,
    const bf* __restrict__ wc1_t, const float* __restrict__ b_c1,
    const float* __restrict__ W_c2, bf* __restrict__ qb, bf* __restrict__ kvb,
    float* __restrict__ outd) {
  // grid 1888 = 8 * 236 -> XCD-chunked
  int id = (blockIdx.x & 7) * 236 + (blockIdx.x >> 3);
  if (id < 96) {
    gemm_core(tabb_bf, winproj, in_proj_b, qb, nullptr, nullptr, nullptr, 0, 0,
              id % 6, id / 6, Dc, 0, 0);
  } else if (id < 1632) {
    int r = id - 96;
    gemm_core(colb, winproj + (size_t)Dc * Dc, in_proj_b + Dc, kvb, nullptr,
              nullptr, nullptr, 0, 0, r % 12, r / 12, 1536, 0, 0);
  } else {
    int r = id - 1632;
    gemm_core(colb, wc1_t, b_c1, nullptr, nullptr, W_c2, outd, Tc, 9, r % 2,
              r / 2, 256, 1, 3);
  }
}

// Single-region GEMM (outproj, t1-head). grid % 8 == 0 assumed.
__global__ __launch_bounds__(256) void gemm_single(
    const bf* __restrict__ A, const bf* __restrict__ Bt,
    const float* __restrict__ bias, bf* __restrict__ Obf,
    float* __restrict__ Of32, const float* __restrict__ w2,
    float* __restrict__ outd, int out_base, int log2rpb, int nbx, int N,
    int leaky, int outmode) {
  int chunk = gridDim.x >> 3;
  int id = (blockIdx.x & 7) * chunk + (blockIdx.x >> 3);
  gemm_core(A, Bt, bias, Obf, Of32, w2, outd, out_base, log2rpb, id % nbx,
            id / nbx, N, leaky, outmode);
}

// ---------------------------------------------------------------------------
// 3) Masked cross-attention (unchanged from R3): one block per (b,t),
//    8 heads x (4 col-groups x 8 lanes), vectorized bf16 loads.
// ---------------------------------------------------------------------------
__global__ __launch_bounds__(256) void attn_kernel(
    const bf* __restrict__ q, const bf* __restrict__ kv,
    const int* __restrict__ col_sorted, const int* __restrict__ offs,
    bf* __restrict__ ctx) {
  int b = blockIdx.x / Tc;
  int t = blockIdx.x % Tc;
  __shared__ float pbuf[Hc][Cc];
  __shared__ float den[Hc];
  __shared__ int cols_s[Cc];
  int tid = threadIdx.x;
  int o0 = offs[b * (Tc + 1) + t];
  int n = offs[b * (Tc + 1) + t + 1] - o0;
  for (int i = tid; i < n; i += 256)
    cols_s[i] = col_sorted[(size_t)b * Cc + o0 + i];
  __syncthreads();
  int h = tid >> 5, l32 = tid & 31, g = l32 >> 3, i8 = l32 & 7;
  const float scale = 0.10206207261596577f;  // 1/sqrt(96)
  float q12[12];
  {
    const ushort* qp =
        (const ushort*)q + ((size_t)b * Tc + t) * Dc + h * DHc + i8 * 12;
    ushort4 u0 = *(const ushort4*)(qp);
    ushort4 u1 = *(const ushort4*)(qp + 4);
    ushort4 u2 = *(const ushort4*)(qp + 8);
    q12[0] = us2f(u0.x); q12[1] = us2f(u0.y); q12[2] = us2f(u0.z); q12[3] = us2f(u0.w);
    q12[4] = us2f(u1.x); q12[5] = us2f(u1.y); q12[6] = us2f(u1.z); q12[7] = us2f(u1.w);
    q12[8] = us2f(u2.x); q12[9] = us2f(u2.y); q12[10] = us2f(u2.z); q12[11] = us2f(u2.w);
  }
  if (n > 0) {
    for (int jb = 0; jb < n; jb += 4) {
      int j = jb + g;
      float s = 0.f;
      if (j < n) {
        const ushort* kp = (const ushort*)kv +
                           ((size_t)b * Cc + cols_s[j]) * 1536 + h * DHc + i8 * 12;
        ushort4 u0 = *(const ushort4*)(kp);
        ushort4 u1 = *(const ushort4*)(kp + 4);
        ushort4 u2 = *(const ushort4*)(kp + 8);
        s += q12[0] * us2f(u0.x) + q12[1] * us2f(u0.y) + q12[2] * us2f(u0.z) +
             q12[3] * us2f(u0.w);
        s += q12[4] * us2f(u1.x) + q12[5] * us2f(u1.y) + q12[6] * us2f(u1.z) +
             q12[7] * us2f(u1.w);
        s += q12[8] * us2f(u2.x) + q12[9] * us2f(u2.y) + q12[10] * us2f(u2.z) +
             q12[11] * us2f(u2.w);
      }
      s += __shfl_xor(s, 1);
      s += __shfl_xor(s, 2);
      s += __shfl_xor(s, 4);
      if (j < n && i8 == 0) pbuf[h][j] = s * scale;
    }
  }
  __syncthreads();
  if (n > 0) {
    float lmax = -3.0e38f;
    for (int j = l32; j < n; j += 32) lmax = fmaxf(lmax, pbuf[h][j]);
#pragma unroll
    for (int m = 16; m >= 1; m >>= 1) lmax = fmaxf(lmax, __shfl_xor(lmax, m));
    float lsum = 0.f;
    for (int j = l32; j < n; j += 32) {
      float e = __expf(pbuf[h][j] - lmax);
      pbuf[h][j] = e;
      lsum += e;
    }
#pragma unroll
    for (int m = 16; m >= 1; m >>= 1) lsum += __shfl_xor(lsum, m);
    if (l32 == 0) den[h] = lsum;
  } else if (l32 == 0) {
    den[h] = (float)Cc;
  }
  __syncthreads();
  int ncols = n > 0 ? n : Cc;
  float a12[12];
#pragma unroll
  for (int d = 0; d < 12; ++d) a12[d] = 0.f;
  for (int jb = 0; jb < ncols; jb += 4) {
    int j = jb + g;
    if (j < ncols) {
      int cj = n > 0 ? cols_s[j] : j;
      float pw = n > 0 ? pbuf[h][j] : 1.f;
      const ushort* vp = (const ushort*)kv + ((size_t)b * Cc + cj) * 1536 +
                         768 + h * DHc + i8 * 12;
      ushort4 u0 = *(const ushort4*)(vp);
      ushort4 u1 = *(const ushort4*)(vp + 4);
      ushort4 u2 = *(const ushort4*)(vp + 8);
      a12[0] += pw * us2f(u0.x); a12[1] += pw * us2f(u0.y);
      a12[2] += pw * us2f(u0.z); a12[3] += pw * us2f(u0.w);
      a12[4] += pw * us2f(u1.x); a12[5] += pw * us2f(u1.y);
      a12[6] += pw * us2f(u1.z); a12[7] += pw * us2f(u1.w);
      a12[8] += pw * us2f(u2.x); a12[9] += pw * us2f(u2.y);
      a12[10] += pw * us2f(u2.z); a12[11] += pw * us2f(u2.w);
    }
  }
#pragma unroll
  for (int d = 0; d < 12; ++d) {
    a12[d] += __shfl_xor(a12[d], 8);
    a12[d] += __shfl_xor(a12[d], 16);
  }
  float inv = 1.0f / den[h];
  if (g == 0) {
    ushort* cp = (ushort*)ctx + ((size_t)b * Tc + t) * Dc + h * DHc + i8 * 12;
    *(ushort4*)(cp) = make_ushort4(f2bf(a12[0] * inv), f2bf(a12[1] * inv),
                                   f2bf(a12[2] * inv), f2bf(a12[3] * inv));
    *(ushort4*)(cp + 4) = make_ushort4(f2bf(a12[4] * inv), f2bf(a12[5] * inv),
                                       f2bf(a12[6] * inv), f2bf(a12[7] * inv));
    *(ushort4*)(cp + 8) = make_ushort4(f2bf(a12[8] * inv), f2bf(a12[9] * inv),
                                       f2bf(a12[10] * inv), f2bf(a12[11] * inv));
  }
}

// ---------------------------------------------------------------------------
// 4) residual add + L2 normalize (f32 in, bf16 out)
// ---------------------------------------------------------------------------
__global__ __launch_bounds__(256) void addnorm_kernel(
    const float* __restrict__ tab, const float* __restrict__ proj,
    bf* __restrict__ tabn) {
  int row = blockIdx.x;
  int tid = threadIdx.x;
  size_t base = (size_t)row * Dc;
  float x0 = tab[base + tid] + proj[base + tid];
  float x1 = tab[base + tid + 256] + proj[base + tid + 256];
  float x2 = tab[base + tid + 512] + proj[base + tid + 512];
  float ss = x0 * x0 + x1 * x1 + x2 * x2;
#pragma unroll
  for (int m = 32; m >= 1; m >>= 1) ss += __shfl_xor(ss, m);
  __shared__ float red[4];
  int wave = tid >> 6, lane = tid & 63;
  if (lane == 0) red[wave] = ss;
  __syncthreads();
  float total = red[0] + red[1] + red[2] + red[3];
  float sc = 1.0f / fmaxf(sqrtf(total), 1e-12f);
  tabn[base + tid] = __float2bfloat16(x0 * sc);
  tabn[base + tid + 256] = __float2bfloat16(x1 * sc);
  tabn[base + tid + 512] = __float2bfloat16(x2 * sc);
}

// ---------------------------------------------------------------------------
extern "C" void kernel_launch(void* const* d_in, const int* in_sizes, int n_in,
                              void* d_out, int out_size, void* d_ws,
                              size_t ws_size, hipStream_t stream) {
  const float* seq = (const float*)d_in[0];
  const int* tab_ids = (const int*)d_in[1];
  const int* col_ids = (const int*)d_in[2];
  const int* t_of_c = (const int*)d_in[3];
  const float* W_tab_pool = (const float*)d_in[4];
  const float* b_tab_pool = (const float*)d_in[5];
  const float* W_col_pool = (const float*)d_in[6];
  const float* b_col_pool = (const float*)d_in[7];
  const float* in_proj_w = (const float*)d_in[8];
  const float* in_proj_b = (const float*)d_in[9];
  const float* out_proj_w = (const float*)d_in[10];
  const float* out_proj_b = (const float*)d_in[11];
  const float* W_t1 = (const float*)d_in[12];
  const float* b_t1 = (const float*)d_in[13];
  const float* W_t2 = (const float*)d_in[14];
  const float* b_t2 = (const float*)d_in[15];
  const float* W_c1 = (const float*)d_in[16];
  const float* b_c1 = (const float*)d_in[17];
  const float* W_c2 = (const float*)d_in[18];
  const float* b_c2 = (const float*)d_in[19];
  float* out = (float*)d_out;

  char* p = (char*)d_ws;
  auto alloc = [&](size_t bytes) -> char* {
    char* r = p;
    p += (bytes + 255) & ~(size_t)255;
    return r;
  };
  const size_t nBT = (size_t)Bc * Tc;   // 2048
  const size_t nBC = (size_t)Bc * Cc;   // 16384
  ushort* seqb = (ushort*)alloc((size_t)Bc * Sc * Dc * 2);  // 100.7 MB
  bf* tabp = (bf*)alloc(nBT * Dc * 2);
  bf* colp = (bf*)alloc(nBC * Dc * 2);
  bf* tabb_bf = (bf*)alloc(nBT * Dc * 2);
  float* tabb_f = (float*)alloc(nBT * Dc * 4);
  bf* colb = (bf*)alloc(nBC * Dc * 2);
  bf* qb = (bf*)alloc(nBT * Dc * 2);
  bf* kvb = (bf*)alloc(nBC * 1536 * 2);
  bf* ctxb = (bf*)alloc(nBT * Dc * 2);
  float* projb = (float*)alloc(nBT * Dc * 4);
  bf* tabn = (bf*)alloc(nBT * Dc * 2);
  bf* wtab_t = (bf*)alloc((size_t)Dc * Dc * 2);
  bf* wcol_t = (bf*)alloc((size_t)Dc * Dc * 2);
  bf* winproj = (bf*)alloc((size_t)3 * Dc * Dc * 2);
  bf* woutproj = (bf*)alloc((size_t)Dc * Dc * 2);
  bf* wt1_t = (bf*)alloc((size_t)256 * Dc * 2);
  bf* wc1_t = (bf*)alloc((size_t)256 * Dc * 2);
  int* col_sorted = (int*)alloc(nBC * 4);
  int* offs = (int*)alloc((size_t)Bc * (Tc + 1) * 4);

  // 1) prep: weights, out-init, seq->bf16, bucket
  prep_kernel<<<28592, 256, 0, stream>>>(
      W_tab_pool, W_col_pool, W_t1, W_c1, in_proj_w, out_proj_w, b_t2, b_c2,
      seq, t_of_c, wtab_t, wcol_t, wt1_t, wc1_t, winproj, woutproj, out,
      seqb, col_sorted, offs);
  // 2) pooling (bf16 gather)
  pool_kernel<<<Bc * (Tc + Cc) / 4, 256, 0, stream>>>(seqb, tab_ids, col_ids,
                                                      (ushort*)tabp,
                                                      (ushort*)colp);
  // 3) pool linears (tab + col, one launch)
  gemm_pools<<<864, 256, 0, stream>>>(tabp, colp, wtab_t, wcol_t, b_tab_pool,
                                      b_col_pool, tabb_bf, tabb_f, colb);
  // 4) q + kv + c1-head (one launch; c1 atomics into bias-inited out)
  gemm_qkvc<<<1888, 256, 0, stream>>>(tabb_bf, colb, winproj, in_proj_b, wc1_t,
                                      b_c1, W_c2, qb, kvb, out);
  // 5) attention
  attn_kernel<<<Bc * Tc, 256, 0, stream>>>(qb, kvb, col_sorted, offs, ctxb);
  // 6) out projection (f32)
  gemm_single<<<96, 256, 0, stream>>>(ctxb, woutproj, out_proj_b, nullptr,
                                      projb, nullptr, nullptr, 0, 0, 6, Dc, 0,
                                      1);
  // 7) residual + L2 norm
  addnorm_kernel<<<nBT, 256, 0, stream>>>(tabb_f, projb, tabn);
  // 8) t1-head (atomics into out)
  gemm_single<<<32, 256, 0, stream>>>(tabn, wt1_t, b_t1, nullptr, nullptr,
                                      W_t2, out, 0, 6, 2, 256, 1, 3);
}